// Round 1
// baseline (1227.132 us; speedup 1.0000x reference)
//
#include <hip/hip_runtime.h>
#include <hip/hip_bf16.h>
#include <math.h>

#define T_TOK 1024
#define DDIM  1024
#define FDIM  2048
#define NEXP  32
#define KTOP  4
#define ESH   33       // 32 routed experts + shared as e=32
#define RTOT  5120     // 4096 routed rows + 1024 shared rows

// workspace layout (int units)
#define WS_CNT   0      // 32 ints (must be zeroed)
#define WS_NWORK 32     // 1
#define WS_OFF   34     // 34
#define WS_WL    68     // up to 256 work tiles
#define WS_TOPI  324    // 4096
#define WS_TOPW  4420   // 4096
#define WS_LTOK  8516   // 5120
#define WS_LW    13636  // 5120
#define WS_H     18816  // bf16 H[5120][2048] starts at byte 4*WS_H

typedef __attribute__((ext_vector_type(8))) short short8;
typedef __attribute__((ext_vector_type(4))) float f32x4;

__device__ inline unsigned pack_bf16x2(float a, float b) {
  unsigned ua = __float_as_uint(a), ub = __float_as_uint(b);
  ua = (ua + 0x8000u) >> 16;
  ub = (ub + 0x8000u) & 0xFFFF0000u;
  return ua | ub;
}

// ---------------- router: logits, top-4, softmax, counts ----------------
__global__ void k_router(const float* __restrict__ x, const float* __restrict__ gw,
                         const float* __restrict__ bias, int* __restrict__ ws) {
  int t = blockIdx.x;
  int lane = threadIdx.x;           // 64
  int e = lane & 31, half = lane >> 5;
  const float* xh = x + (size_t)t * DDIM + half * (DDIM / 2);
  const float* gr = gw + (size_t)e * DDIM + half * (DDIM / 2);
  float acc = 0.f;
  for (int d = 0; d < DDIM / 2; d += 4) {
    float4 xv = *(const float4*)(xh + d);
    float4 gv = *(const float4*)(gr + d);
    acc += xv.x * gv.x + xv.y * gv.y + xv.z * gv.z + xv.w * gv.w;
  }
  acc += __shfl_xor(acc, 32, 64);
  __shared__ float lg[NEXP];
  if (lane < NEXP) lg[lane] = acc + bias[lane];
  __syncthreads();
  if (lane == 0) {
    int idx[KTOP]; float val[KTOP]; unsigned used = 0;
    for (int s = 0; s < KTOP; ++s) {
      float best = -1e30f; int bi = 0;
      for (int j = 0; j < NEXP; ++j)
        if (!((used >> j) & 1u) && lg[j] > best) { best = lg[j]; bi = j; }
      used |= 1u << bi; idx[s] = bi; val[s] = best;
    }
    float m = val[0], ssum = 0.f, w[KTOP];
    for (int s = 0; s < KTOP; ++s) { w[s] = __expf(val[s] - m); ssum += w[s]; }
    for (int s = 0; s < KTOP; ++s) {
      ws[WS_TOPI + t * KTOP + s] = idx[s];
      ((float*)ws)[WS_TOPW + t * KTOP + s] = w[s] / ssum;
      atomicAdd(&ws[WS_CNT + idx[s]], 1);
    }
  }
}

// ---------------- post: offsets, worklist, token lists, counts/lb out ----------------
__global__ void k_post(int* __restrict__ ws, float* __restrict__ out) {
  __shared__ int off_s[ESH + 1];
  __shared__ int cur_s[ESH];
  int tid = threadIdx.x;
  if (tid == 0) {
    int o = 0;
    for (int e = 0; e < NEXP; ++e) { off_s[e] = o; o += ws[WS_CNT + e]; }
    off_s[32] = o; off_s[33] = o + T_TOK;
    int w = 0;
    for (int e = 0; e < ESH; ++e) {
      int n = (e < NEXP) ? ws[WS_CNT + e] : T_TOK;
      int tiles = (n + 31) >> 5;
      for (int mt = 0; mt < tiles; ++mt) ws[WS_WL + w++] = (e << 6) | mt;
    }
    ws[WS_NWORK] = w;
    for (int i = 0; i <= ESH; ++i) ws[WS_OFF + i] = off_s[i];
    float mean = 0.f;
    for (int e = 0; e < NEXP; ++e) mean += (float)ws[WS_CNT + e];
    mean *= (1.f / NEXP);
    float var = 0.f;
    for (int e = 0; e < NEXP; ++e) { float d = (float)ws[WS_CNT + e] - mean; var += d * d; }
    var *= (1.f / NEXP);
    for (int e = 0; e < NEXP; ++e) out[(size_t)T_TOK * DDIM + e] = (float)ws[WS_CNT + e];
    out[(size_t)T_TOK * DDIM + NEXP] = sqrtf(var) / (mean + 1e-6f);
  }
  if (tid < ESH) cur_s[tid] = 0;
  __syncthreads();
  if (tid < T_TOK) {
    for (int s = 0; s < KTOP; ++s) {
      int e = ws[WS_TOPI + tid * KTOP + s];
      int p = atomicAdd(&cur_s[e], 1);
      ws[WS_LTOK + off_s[e] + p] = tid;
      ((float*)ws)[WS_LW + off_s[e] + p] = ((const float*)ws)[WS_TOPW + tid * KTOP + s];
    }
    ws[WS_LTOK + off_s[32] + tid] = tid;
    ((float*)ws)[WS_LW + off_s[32] + tid] = 1.f;
  }
}

// ---------------- stage1: H = silu(X Wg^T) * (X Wu^T) ----------------
__global__ __launch_bounds__(256) void k_stage1(
    const float* __restrict__ x, const float* __restrict__ wg, const float* __restrict__ wu,
    const float* __restrict__ wsg, const float* __restrict__ wsu,
    const int* __restrict__ ws, __hip_bfloat16* __restrict__ H) {
  int wid = blockIdx.x;
  if (wid >= ws[WS_NWORK]) return;
  int wl = ws[WS_WL + wid];
  int e = wl >> 6, mt = wl & 63;
  int off_e = ws[WS_OFF + e];
  int n_e = ws[WS_OFF + e + 1] - off_e;
  int m0 = off_e + mt * 32;
  int nb = blockIdx.y * 64;
  const float* wgp = (e < NEXP) ? wg + (size_t)e * FDIM * DDIM : wsg;
  const float* wup = (e < NEXP) ? wu + (size_t)e * FDIM * DDIM : wsu;

  __shared__ int tok_s[32];
  __shared__ ushort a_s[8][32][8];
  __shared__ ushort bg_s[8][64][8];
  __shared__ ushort bu_s[8][64][8];

  int tid = threadIdx.x;
  if (tid < 32) {
    int idx = mt * 32 + tid;
    tok_s[tid] = ws[WS_LTOK + off_e + (idx < n_e ? idx : 0)];
  }
  __syncthreads();

  int kgA = tid & 7, mA = tid >> 3;
  const float* aptr = x + (size_t)tok_s[mA] * DDIM + kgA * 8;
  int kgB = tid & 7, nB = tid >> 3;
  f32x4 accg0 = {0,0,0,0}, accg1 = {0,0,0,0}, accu0 = {0,0,0,0}, accu1 = {0,0,0,0};
  int wave = tid >> 6, lane = tid & 63;
  int msub = wave & 1, npair = wave >> 1;
  int lm = lane & 15, lk = lane >> 4;

  for (int k0 = 0; k0 < DDIM; k0 += 64) {
    {
      float4 f0 = *(const float4*)(aptr + k0);
      float4 f1 = *(const float4*)(aptr + k0 + 4);
      uint4 p; p.x = pack_bf16x2(f0.x, f0.y); p.y = pack_bf16x2(f0.z, f0.w);
      p.z = pack_bf16x2(f1.x, f1.y); p.w = pack_bf16x2(f1.z, f1.w);
      *(uint4*)&a_s[kgA][mA][0] = p;
    }
#pragma unroll
    for (int r = 0; r < 2; ++r) {
      int n = nB + r * 32;
      const float* gsrc = wgp + (size_t)(nb + n) * DDIM + k0 + kgB * 8;
      float4 f0 = *(const float4*)gsrc; float4 f1 = *(const float4*)(gsrc + 4);
      uint4 p; p.x = pack_bf16x2(f0.x, f0.y); p.y = pack_bf16x2(f0.z, f0.w);
      p.z = pack_bf16x2(f1.x, f1.y); p.w = pack_bf16x2(f1.z, f1.w);
      *(uint4*)&bg_s[kgB][n][0] = p;
      const float* usrc = wup + (size_t)(nb + n) * DDIM + k0 + kgB * 8;
      f0 = *(const float4*)usrc; f1 = *(const float4*)(usrc + 4);
      p.x = pack_bf16x2(f0.x, f0.y); p.y = pack_bf16x2(f0.z, f0.w);
      p.z = pack_bf16x2(f1.x, f1.y); p.w = pack_bf16x2(f1.z, f1.w);
      *(uint4*)&bu_s[kgB][n][0] = p;
    }
    __syncthreads();
#pragma unroll
    for (int ks = 0; ks < 2; ++ks) {
      short8 av  = *(short8*)&a_s[ks * 4 + lk][msub * 16 + lm][0];
      short8 bg0 = *(short8*)&bg_s[ks * 4 + lk][npair * 32 + lm][0];
      short8 bu0 = *(short8*)&bu_s[ks * 4 + lk][npair * 32 + lm][0];
      short8 bg1 = *(short8*)&bg_s[ks * 4 + lk][npair * 32 + 16 + lm][0];
      short8 bu1 = *(short8*)&bu_s[ks * 4 + lk][npair * 32 + 16 + lm][0];
      accg0 = __builtin_amdgcn_mfma_f32_16x16x32_bf16(av, bg0, accg0, 0, 0, 0);
      accu0 = __builtin_amdgcn_mfma_f32_16x16x32_bf16(av, bu0, accu0, 0, 0, 0);
      accg1 = __builtin_amdgcn_mfma_f32_16x16x32_bf16(av, bg1, accg1, 0, 0, 0);
      accu1 = __builtin_amdgcn_mfma_f32_16x16x32_bf16(av, bu1, accu1, 0, 0, 0);
    }
    __syncthreads();
  }
#pragma unroll
  for (int ns = 0; ns < 2; ++ns) {
    f32x4 g = ns ? accg1 : accg0;
    f32x4 u = ns ? accu1 : accu0;
#pragma unroll
    for (int r = 0; r < 4; ++r) {
      int lrow = msub * 16 + lk * 4 + r;
      if (mt * 32 + lrow < n_e) {
        float gv = g[r];
        float hv = (gv / (1.f + __expf(-gv))) * u[r];
        H[(size_t)(m0 + lrow) * FDIM + nb + npair * 32 + ns * 16 + lm] = __float2bfloat16(hv);
      }
    }
  }
}

// ---------------- stage2: Y = H Wd^T, weighted scatter-add ----------------
__global__ __launch_bounds__(256) void k_stage2(
    const float* __restrict__ wd, const float* __restrict__ wsd,
    const int* __restrict__ ws, const __hip_bfloat16* __restrict__ H,
    float* __restrict__ out) {
  int wid = blockIdx.x;
  if (wid >= ws[WS_NWORK]) return;
  int wl = ws[WS_WL + wid];
  int e = wl >> 6, mt = wl & 63;
  int off_e = ws[WS_OFF + e];
  int n_e = ws[WS_OFF + e + 1] - off_e;
  int m0 = off_e + mt * 32;
  int nb = blockIdx.y * 64;
  const float* wdp = (e < NEXP) ? wd + (size_t)e * DDIM * FDIM : wsd;

  __shared__ int tok_s[32];
  __shared__ float w_s[32];
  __shared__ ushort a_s[8][32][8];
  __shared__ ushort b_s[8][64][8];

  int tid = threadIdx.x;
  if (tid < 32) {
    int idx = mt * 32 + tid;
    int cl = idx < n_e ? idx : 0;
    tok_s[tid] = ws[WS_LTOK + off_e + cl];
    w_s[tid]   = ((const float*)ws)[WS_LW + off_e + cl];
  }
  __syncthreads();

  int kgA = tid & 7, mA = tid >> 3;
  const __hip_bfloat16* aptr = H + (size_t)(m0 + mA) * FDIM + kgA * 8;
  int kgB = tid & 7, nB = tid >> 3;
  f32x4 acc0 = {0,0,0,0}, acc1 = {0,0,0,0};
  int wave = tid >> 6, lane = tid & 63;
  int msub = wave & 1, npair = wave >> 1;
  int lm = lane & 15, lk = lane >> 4;

  for (int k0 = 0; k0 < FDIM; k0 += 64) {
    *(uint4*)&a_s[kgA][mA][0] = *(const uint4*)(aptr + k0);
#pragma unroll
    for (int r = 0; r < 2; ++r) {
      int n = nB + r * 32;
      const float* src = wdp + (size_t)(nb + n) * FDIM + k0 + kgB * 8;
      float4 f0 = *(const float4*)src; float4 f1 = *(const float4*)(src + 4);
      uint4 p; p.x = pack_bf16x2(f0.x, f0.y); p.y = pack_bf16x2(f0.z, f0.w);
      p.z = pack_bf16x2(f1.x, f1.y); p.w = pack_bf16x2(f1.z, f1.w);
      *(uint4*)&b_s[kgB][n][0] = p;
    }
    __syncthreads();
#pragma unroll
    for (int ks = 0; ks < 2; ++ks) {
      short8 av = *(short8*)&a_s[ks * 4 + lk][msub * 16 + lm][0];
      short8 b0 = *(short8*)&b_s[ks * 4 + lk][npair * 32 + lm][0];
      short8 b1 = *(short8*)&b_s[ks * 4 + lk][npair * 32 + 16 + lm][0];
      acc0 = __builtin_amdgcn_mfma_f32_16x16x32_bf16(av, b0, acc0, 0, 0, 0);
      acc1 = __builtin_amdgcn_mfma_f32_16x16x32_bf16(av, b1, acc1, 0, 0, 0);
    }
    __syncthreads();
  }
#pragma unroll
  for (int ns = 0; ns < 2; ++ns) {
    f32x4 a = ns ? acc1 : acc0;
#pragma unroll
    for (int r = 0; r < 4; ++r) {
      int lrow = msub * 16 + lk * 4 + r;
      if (mt * 32 + lrow < n_e) {
        int t = tok_s[lrow];
        atomicAdd(&out[(size_t)t * DDIM + nb + npair * 32 + ns * 16 + lm], w_s[lrow] * a[r]);
      }
    }
  }
}

extern "C" void kernel_launch(void* const* d_in, const int* in_sizes, int n_in,
                              void* d_out, int out_size, void* d_ws, size_t ws_size,
                              hipStream_t stream) {
  const float* x    = (const float*)d_in[0];
  const float* gw   = (const float*)d_in[1];
  const float* bias = (const float*)d_in[2];
  const float* wg   = (const float*)d_in[3];
  const float* wu   = (const float*)d_in[4];
  const float* wd   = (const float*)d_in[5];
  const float* wsg  = (const float*)d_in[6];
  const float* wsu  = (const float*)d_in[7];
  const float* wsd  = (const float*)d_in[8];
  float* out = (float*)d_out;
  int* ws = (int*)d_ws;
  __hip_bfloat16* H = (__hip_bfloat16*)((char*)d_ws + (size_t)WS_H * 4);

  hipMemsetAsync(d_out, 0, (size_t)out_size * sizeof(float), stream);
  hipMemsetAsync(d_ws, 0, 32 * sizeof(int), stream);   // zero expert counts
  k_router<<<T_TOK, 64, 0, stream>>>(x, gw, bias, ws);
  k_post<<<1, 1024, 0, stream>>>(ws, out);
  k_stage1<<<dim3(224, 32), 256, 0, stream>>>(x, wg, wu, wsg, wsu, ws, H);
  k_stage2<<<dim3(224, 16), 256, 0, stream>>>(wd, wsd, ws, H, out);
}